// Round 6
// baseline (47.931 us; speedup 1.0000x reference)
//
#include <hip/hip_runtime.h>

// ConvDatapath: bit-serial crossbar conv with per-chunk ADC quantization.
// SINGLE self-contained kernel. 196 blocks x 1024 threads; each block owns
// 2 x-row-tiles (32 im2col rows) and computes all 16 output tiles for them.
// All quantized fragments live in LDS (130,688 B/block); no workspace, no
// second launch, no inter-block dependency.
// Nx = 6272 im2col rows, Ny = 128, K = 576 (5 chunks of 116).

#define NX    6272
#define NY    128
#define KDIM  576
#define NCH   5
#define NPB   116

typedef int i32x4 __attribute__((ext_vector_type(4)));

// fragment byte offset within one tile's staging area: [chunk][ks][ln][j]
// (2048 B per chunk, 10,240 B per tile). lane ln = lgrp*16 + rowInTile,
// j = kk&15, ks = kk>=64 — matches mfma_i32_16x16x64_i8 operand layout.
__device__ __forceinline__ int stg_off(int chunk, int kk, int rl) {
    int ks   = kk >> 6;
    int lgrp = (kk >> 4) & 3;
    int j    = kk & 15;
    return (chunk * 2 + ks) * 1024 + (lgrp * 16 + rl) * 16 + j;
}

__device__ __forceinline__ i32x4 slice2b(i32x4 v, int sh) {
    i32x4 r;
    r[0] = (int)(((unsigned)v[0] >> sh) & 0x03030303u);
    r[1] = (int)(((unsigned)v[1] >> sh) & 0x03030303u);
    r[2] = (int)(((unsigned)v[2] >> sh) & 0x03030303u);
    r[3] = (int)(((unsigned)v[3] >> sh) & 0x03030303u);
    return r;
}

// per-row quantizer stats (bit-identical op order to the reference)
__device__ __forceinline__ void rowstats(float (&v)[9], float& step,
                                         float& mn_, float& sm_) {
    float mn = v[0], mx = v[0], sm = 0.f;
#pragma unroll
    for (int r = 0; r < 9; r++) { mn = fminf(mn, v[r]); mx = fmaxf(mx, v[r]); sm += v[r]; }
#pragma unroll
    for (int off = 32; off > 0; off >>= 1) {
        mn = fminf(mn, __shfl_xor(mn, off));
        mx = fmaxf(mx, __shfl_xor(mx, off));
        sm += __shfl_xor(sm, off);
    }
    step = (mx - mn) / 255.0f;
    mn_ = mn; sm_ = sm;
}

// scatter one quantized row into a tile staging area + its K padding
__device__ __forceinline__ void scatter_row(unsigned char* stg, float (&v)[9],
                                            float mn, float step, int rl, int lane) {
#pragma unroll
    for (int r = 0; r < 9; r++) {
        int t2 = lane * 9 + r;
        int q = (int)rintf((v[r] - mn) / step);
        q = q < 0 ? 0 : (q > 255 ? 255 : q);
        int chunk = t2 / NPB, kk = t2 - chunk * NPB;
        stg[stg_off(chunk, kk, rl)] = (unsigned char)q;
    }
    // per-row K padding: chunks 0..3 pad kk 116..127 (12 each), chunk 4 pads 112..127
    int chunk, kk;
    if (lane < 48) { chunk = lane / 12; kk = NPB + lane % 12; }
    else           { chunk = 4;        kk = 112 + (lane - 48); }
    stg[stg_off(chunk, kk, rl)] = 0;
}

// LDS layout (dynamic, 130,688 B):
//   stgW   at      0 : 8 ctiles  x 10,240 = 81,920
//   stgX   at  81,920: 2 rtiles  x 10,240 = 20,480
//   scal   at 102,400: xsc[32] xof[32] xsm[32] wsc[128] wof[128] wsm[128] = 1,920
//   xs2    at 104,320: float[64][103]  ([cin][kh*34+c])            = 26,368
extern __shared__ unsigned char lds[];

__global__ __launch_bounds__(1024) void k_all(
    const float* __restrict__ x, const float* __restrict__ w,
    float* __restrict__ out)
{
    unsigned char* stgW = lds;
    unsigned char* stgX = lds + 81920;
    float* xsc = (float*)(lds + 102400);
    float* xof = xsc + 32;  float* xsm = xof + 32;
    float* wsc = xsm + 32;  float* wof = wsc + 128;  float* wsm = wof + 128;
    float* xs2 = (float*)(lds + 104320);

    int blk = blockIdx.x;                 // 0..195
    int tid = threadIdx.x;
    int wv = tid >> 6, lane = tid & 63;
    int b = blk >= 98 ? 1 : 0;
    int pos_base = (blk - 98 * b) * 32;   // flat h*56+w of first of 32 rows
    const float* xb = x + (size_t)(b * 64) * 3136;

    // ---- phase A: stage x stripe: xs2[cin][kh*34+c] = x[cin][h(g)-1+kh][w(g)],
    //      g = pos_base + c - 1 (flat-position trick -> coalesced runs)
    for (int i = tid; i < 64 * 102; i += 1024) {
        int cin = i / 102, rem = i - cin * 102;
        int kh = rem / 34, c = rem - kh * 34;
        int g = pos_base + c - 1;
        float vv = 0.f;
        if (g >= 0 && g < 3136) {
            int hg = g / 56, wg = g - hg * 56;
            int r = hg - 1 + kh;
            if (r >= 0 && r < 56) vv = xb[cin * 3136 + r * 56 + wg];
        }
        xs2[cin * 103 + rem] = vv;
    }
    __syncthreads();

    // ---- phase B: x quantization, 2 rows per wave (lane == cin)
#pragma unroll
    for (int qi = 0; qi < 2; qi++) {
        int i = wv * 2 + qi;              // 0..31: row within block
        int pos = pos_base + i;
        int w_ = pos - (pos / 56) * 56;
        float v[9];
#pragma unroll
        for (int kh = 0; kh < 3; kh++)
#pragma unroll
            for (int kw = 0; kw < 3; kw++) {
                int ww = w_ - 1 + kw;
                v[kh * 3 + kw] = (ww >= 0 && ww < 56)
                               ? xs2[lane * 103 + kh * 34 + i + kw] : 0.f;
            }
        float step, mn, sm;
        rowstats(v, step, mn, sm);
        if (lane == 0) { xsc[i] = step; xof[i] = mn; xsm[i] = sm; }
        scatter_row(stgX + (i >> 4) * 10240, v, mn, step, i & 15, lane);
    }

    // ---- phase C: w quantization (redundant per block), 8 rows per wave
#pragma unroll
    for (int qi = 0; qi < 8; qi++) {
        int row = wv * 8 + qi;            // 0..127
        const float* wr = w + row * KDIM;
        float v[9];
#pragma unroll
        for (int r = 0; r < 9; r++) v[r] = wr[lane * 9 + r];
        float step, mn, sm;
        rowstats(v, step, mn, sm);
        if (lane == 0) { wsc[row] = step; wof[row] = mn; wsm[row] = sm; }
        scatter_row(stgW + (row >> 4) * 10240, v, mn, step, row & 15, lane);
    }
    __syncthreads();

    // ---- phase D: crossbar MFMA + ADC + recombine + dequant
    // wave -> one output tile: rt = wv>>3 (x tile), ctl = wv&7 (w tile).
    // Swapped operands (A=W, B=X) so C/D col (lane&15) = x position.
    int rt = wv >> 3, ctl = wv & 7;
    const unsigned char* Wb = stgW + ctl * 10240;
    const unsigned char* Xb = stgX + rt * 10240;

    i32x4 acc = {0, 0, 0, 0};
    const i32x4 zero = {0, 0, 0, 0};

    for (int chunk = 0; chunk < NCH; chunk++) {
        const i32x4* Ax = (const i32x4*)(Xb + chunk * 2048 + lane * 16);
        const i32x4* Aw = (const i32x4*)(Wb + chunk * 2048 + lane * 16);
        i32x4 ar0 = Ax[0], ar1 = Ax[64];   // x fragment ks=0/1 (+1024 B)
        i32x4 br0 = Aw[0], br1 = Aw[64];   // w fragment ks=0/1

        i32x4 ws_sl[4][2];
#pragma unroll
        for (int ws = 0; ws < 4; ws++) {
            ws_sl[ws][0] = slice2b(br0, 6 - 2 * ws);
            ws_sl[ws][1] = slice2b(br1, 6 - 2 * ws);
        }
#pragma unroll
        for (int is = 0; is < 4; is++) {
            int ish = 6 - 2 * is;
            i32x4 b0 = slice2b(ar0, ish);
            i32x4 b1 = slice2b(ar1, ish);
#pragma unroll
            for (int ws = 0; ws < 4; ws++) {
                i32x4 d = __builtin_amdgcn_mfma_i32_16x16x64_i8(ws_sl[ws][0], b0, zero, 0, 0, 0);
                d = __builtin_amdgcn_mfma_i32_16x16x64_i8(ws_sl[ws][1], b1, d, 0, 0, 0);
                int sh = ish + (6 - 2 * ws);
#pragma unroll
                for (int r = 0; r < 4; r++) {
                    int z = d[r];
                    z = z > 1024 ? 1024 : z;                 // ADC clip (z >= 0)
                    int r4 = (z + 1 + ((z >> 2) & 1)) & ~3;  // round-half-even to mult of 4
                    acc[r] += r4 << sh;                      // 2^(ish+wsh)
                }
            }
        }
    }

    // epilogue: D[row = w-row (g*4+r), col = x-row (cl)]; coalesced 64B runs
    int cl = lane & 15, g = lane >> 4;
    int i_loc = rt * 16 + cl;             // block-local x row 0..31
    float xs = xsc[i_loc], xo = xof[i_loc], xsmv = xsm[i_loc];
    int hw = pos_base + i_loc;
#pragma unroll
    for (int r = 0; r < 4; r++) {
        int wrow = ctl * 16 + g * 4 + r;
        float tt = ((float)acc[r] * xs) * wsc[wrow];
        float res = ((tt + xo * wsm[wrow]) + wof[wrow] * xsmv)
                  - (xo * wof[wrow]) * 576.0f;
        out[(b * 128 + wrow) * 3136 + hw] = res;
    }
}

extern "C" void kernel_launch(void* const* d_in, const int* in_sizes, int n_in,
                              void* d_out, int out_size, void* d_ws, size_t ws_size,
                              hipStream_t stream) {
    const float* x = (const float*)d_in[0];   // [2][64][56][56]
    const float* w = (const float*)d_in[1];   // [128][64][3][3]
    float* out = (float*)d_out;               // [2][128][56][56]

    // best-effort opt-in for >64KB dynamic LDS (no-op if unsupported;
    // host-side call, not part of stream / graph capture)
    (void)hipFuncSetAttribute((const void*)k_all,
                              hipFuncAttributeMaxDynamicSharedMemorySize, 130688);

    hipLaunchKernelGGL(k_all, dim3(196), dim3(1024), 130688, stream, x, w, out);
}

// Round 7
// 41.187 us; speedup vs baseline: 1.1637x; 1.1637x over previous
//
#include <hip/hip_runtime.h>

// ConvDatapath: bit-serial crossbar conv with per-chunk ADC quantization.
// Single kernel, 196 blocks x 1024 threads. Each block: 2 x-row-tiles (32
// im2col rows) x all 8 w-tiles. Quantized bytes are written to a row-major
// LDS scratch with dword-aligned conflict-free writes, then repacked into
// MFMA fragment layout with b128 moves (dst lane-linear, src 2-way).
// Nx = 6272, Ny = 128, K = 576 (5 chunks of 116, padded to 128).

#define NY    128
#define KDIM  576
#define NCH   5
#define NPB   116

typedef int i32x4 __attribute__((ext_vector_type(4)));
typedef float f32x4 __attribute__((ext_vector_type(4)));

// LDS layout (byte offsets), dynamic total 151,680:
//  stgW  @ 0       : 81,920  (8 tiles x 10,240 fragment bytes)
//  stgX  @ 81,920  : 20,480  (2 tiles)
//  scal  @ 102,400 : 1,920   (xsc/xof/xsm[32], wsc/wof/wsm[128])
//  scr   @ 104,320 : scrX 2x10,496 = 20,992   (phases A/B, repX)
//                    scrW4 4x10,496 = 41,984  (phases C1/C2, aliases scrX+xs2)
//  xs2   @ 125,312 : 26,368  (float[64][103], phases A/B only)
extern __shared__ unsigned char lds[];

__device__ __forceinline__ i32x4 slice2b(i32x4 v, int sh) {
    i32x4 r;
    r[0] = (int)(((unsigned)v[0] >> sh) & 0x03030303u);
    r[1] = (int)(((unsigned)v[1] >> sh) & 0x03030303u);
    r[2] = (int)(((unsigned)v[2] >> sh) & 0x03030303u);
    r[3] = (int)(((unsigned)v[3] >> sh) & 0x03030303u);
    return r;
}

// quantize one row distributed over a 16-lane group (lane i16 holds k =
// 36*i16..+35, in k-order). Stats via 4-step shuffle (exact min/max).
// Writes 9 dword-aligned b32 to row-major scratch (col = k + 12*chunk).
__device__ __forceinline__ void quant36(const float (&v)[36], unsigned char* rowp,
                                        int i16, float* sc_s, float* of_s,
                                        float* sm_s, int sidx)
{
    float mn = v[0], mx = v[0], sm = 0.f;
#pragma unroll
    for (int m = 0; m < 36; m++) { mn = fminf(mn, v[m]); mx = fmaxf(mx, v[m]); sm += v[m]; }
#pragma unroll
    for (int off = 1; off < 16; off <<= 1) {
        mn = fminf(mn, __shfl_xor(mn, off));
        mx = fmaxf(mx, __shfl_xor(mx, off));
        sm += __shfl_xor(sm, off);
    }
    float step = (mx - mn) / 255.0f;
    if (i16 == 0) { sc_s[sidx] = step; of_s[sidx] = mn; sm_s[sidx] = sm; }
    int k0 = i16 * 36;
#pragma unroll
    for (int d = 0; d < 9; d++) {
        unsigned int dw = 0;
#pragma unroll
        for (int mb = 0; mb < 4; mb++) {
            int q = (int)rintf((v[d * 4 + mb] - mn) / step);
            q = q < 0 ? 0 : (q > 255 ? 255 : q);
            dw |= (unsigned)q << (8 * mb);
        }
        int kd = k0 + d * 4;
        int ch = kd / NPB;                       // chunk (magic-mul)
        *(unsigned int*)(rowp + kd + 12 * ch) = dw;   // col = ch*128 + kd%116
    }
}

__global__ __launch_bounds__(1024) void k_all(
    const float* __restrict__ x, const float* __restrict__ w,
    float* __restrict__ out)
{
    unsigned char* stgW = lds;
    unsigned char* stgX = lds + 81920;
    float* xsc = (float*)(lds + 102400);
    float* xof = xsc + 32;  float* xsm = xof + 32;
    float* wsc = xsm + 32;  float* wof = wsc + 128;  float* wsm = wof + 128;
    unsigned char* scr = lds + 104320;
    float* xs2 = (float*)(lds + 125312);

    int tid = threadIdx.x, wv = tid >> 6, lane = tid & 63;
    int g = lane >> 4, i16 = lane & 15;
    int blk = blockIdx.x;
    int b = blk >= 98 ? 1 : 0;
    int pos_base = (blk - 98 * b) * 32;
    const float* xb = x + (size_t)(b * 64) * 3136;

    // ---- phase A: stage xs2[cin][kh*34+c] + zero scrX pad dwords
    for (int i = tid; i < 64 * 102; i += 1024) {
        int cin = i / 102, rem = i - cin * 102;
        int kh = rem / 34;
        int gg = pos_base + (rem - kh * 34) - 1;
        float vv = 0.f;
        if (gg >= 0 && gg < 3136) {
            int hg = gg / 56, wg = gg - hg * 56;
            int r = hg - 1 + kh;
            if (r >= 0 && r < 56) vv = xb[cin * 3136 + r * 56 + wg];
        }
        xs2[cin * 103 + rem] = vv;
    }
    if (tid < 512) {   // scrX pads: 2 tiles x 16 rows x 16 dwords
        int tile = tid >> 8, rl = (tid >> 4) & 15, dwp = tid & 15;
        int col = dwp < 12 ? (dwp / 3) * 128 + 116 + (dwp % 3) * 4
                           : 624 + (dwp - 12) * 4;
        *(unsigned int*)(scr + tile * 10496 + rl * 656 + col) = 0u;
    }
    __syncthreads();

    // ---- phase B: x quantization, waves 0..7, 4 rows each (16 lanes/row)
    if (wv < 8) {
        int i = wv * 4 + g;                   // block-local row 0..31
        int pos = pos_base + i;
        int w_ = pos - (pos / 56) * 56;
        float v[36];
#pragma unroll
        for (int m = 0; m < 36; m++) {
            int r9 = m % 9, kh = r9 / 3, kw = r9 - kh * 3;
            int cin = i16 * 4 + m / 9;
            int ww = w_ - 1 + kw;
            v[m] = (ww >= 0 && ww < 56) ? xs2[cin * 103 + kh * 34 + i + kw] : 0.f;
        }
        quant36(v, scr + (i >> 4) * 10496 + (i & 15) * 656, i16, xsc, xof, xsm, i);
    }
    __syncthreads();

    // ---- repack X: 2 tiles x 640 16B runs; dst lane-linear, src stride 656
    for (int idx = tid; idx < 2 * 640; idx += 1024) {
        int tile = idx / 640, rr = idx - tile * 640;
        int u = rr >> 4, rl = rr & 15;
        *(i32x4*)(stgX + tile * 10240 + rr * 16) =
            *(const i32x4*)(scr + tile * 10496 + rl * 656 + u * 16);
    }
    __syncthreads();

    // ---- phase C1: w rows 0..63 -> scrW4 tiles 0..3 (+ zero scrW pads)
    {
        int tile = tid >> 8, rl = (tid >> 4) & 15, dwp = tid & 15;
        int col = dwp < 12 ? (dwp / 3) * 128 + 116 + (dwp % 3) * 4
                           : 624 + (dwp - 12) * 4;
        *(unsigned int*)(scr + tile * 10496 + rl * 656 + col) = 0u;
    }
    {
        int row = wv * 4 + g;                 // 0..63
        const float* wr = w + (size_t)row * KDIM + i16 * 36;
        float v[36];
#pragma unroll
        for (int d = 0; d < 9; d++) {
            f32x4 t = *(const f32x4*)(wr + d * 4);
            v[d*4+0] = t[0]; v[d*4+1] = t[1]; v[d*4+2] = t[2]; v[d*4+3] = t[3];
        }
        quant36(v, scr + (row >> 4) * 10496 + (row & 15) * 656, i16, wsc, wof, wsm, row);
    }
    __syncthreads();

    // ---- repack W tiles 0..3
    for (int idx = tid; idx < 4 * 640; idx += 1024) {
        int tile = idx / 640, rr = idx - tile * 640;
        int u = rr >> 4, rl = rr & 15;
        *(i32x4*)(stgW + tile * 10240 + rr * 16) =
            *(const i32x4*)(scr + tile * 10496 + rl * 656 + u * 16);
    }
    __syncthreads();

    // ---- phase C2: w rows 64..127 -> scrW4 tiles 0..3 (pads persist)
    {
        int row = 64 + wv * 4 + g;
        const float* wr = w + (size_t)row * KDIM + i16 * 36;
        float v[36];
#pragma unroll
        for (int d = 0; d < 9; d++) {
            f32x4 t = *(const f32x4*)(wr + d * 4);
            v[d*4+0] = t[0]; v[d*4+1] = t[1]; v[d*4+2] = t[2]; v[d*4+3] = t[3];
        }
        quant36(v, scr + ((row - 64) >> 4) * 10496 + (row & 15) * 656, i16, wsc, wof, wsm, row);
    }
    __syncthreads();

    // ---- repack W tiles 4..7
    for (int idx = tid; idx < 4 * 640; idx += 1024) {
        int tile = idx / 640, rr = idx - tile * 640;
        int u = rr >> 4, rl = rr & 15;
        *(i32x4*)(stgW + (4 + tile) * 10240 + rr * 16) =
            *(const i32x4*)(scr + tile * 10496 + rl * 656 + u * 16);
    }
    __syncthreads();

    // ---- phase D: crossbar MFMA + ADC + recombine + dequant
    // wave -> one output tile: rt = wv>>3 (x tile), ctl = wv&7 (w tile).
    // Swapped operands (A=W, B=X) so C/D col (lane&15) = x position.
    int rt = wv >> 3, ctl = wv & 7;
    const unsigned char* Wb = stgW + ctl * 10240;
    const unsigned char* Xb = stgX + rt * 10240;

    i32x4 acc = {0, 0, 0, 0};
    const i32x4 zero = {0, 0, 0, 0};

    for (int chunk = 0; chunk < NCH; chunk++) {
        const i32x4* Ax = (const i32x4*)(Xb + chunk * 2048 + lane * 16);
        const i32x4* Aw = (const i32x4*)(Wb + chunk * 2048 + lane * 16);
        i32x4 ar0 = Ax[0], ar1 = Ax[64];   // x fragment ks=0/1 (+1024 B)
        i32x4 br0 = Aw[0], br1 = Aw[64];   // w fragment ks=0/1

        i32x4 ws_sl[4][2];
#pragma unroll
        for (int ws = 0; ws < 4; ws++) {
            ws_sl[ws][0] = slice2b(br0, 6 - 2 * ws);
            ws_sl[ws][1] = slice2b(br1, 6 - 2 * ws);
        }
#pragma unroll
        for (int is = 0; is < 4; is++) {
            int ish = 6 - 2 * is;
            i32x4 b0 = slice2b(ar0, ish);
            i32x4 b1 = slice2b(ar1, ish);
#pragma unroll
            for (int ws = 0; ws < 4; ws++) {
                i32x4 d = __builtin_amdgcn_mfma_i32_16x16x64_i8(ws_sl[ws][0], b0, zero, 0, 0, 0);
                d = __builtin_amdgcn_mfma_i32_16x16x64_i8(ws_sl[ws][1], b1, d, 0, 0, 0);
                int sh = ish + (6 - 2 * ws);
#pragma unroll
                for (int r = 0; r < 4; r++) {
                    int z = d[r];
                    z = z > 1024 ? 1024 : z;                 // ADC clip (z >= 0)
                    int r4 = (z + 1 + ((z >> 2) & 1)) & ~3;  // round-half-even to mult of 4
                    acc[r] += r4 << sh;                      // 2^(ish+wsh)
                }
            }
        }
    }

    // epilogue: D[row = w-row (g*4+r), col = x-row (i16)]; coalesced 64B runs
    int i_loc = rt * 16 + i16;            // block-local x row 0..31
    float xs = xsc[i_loc], xo = xof[i_loc], xsmv = xsm[i_loc];
    int hw = pos_base + i_loc;
#pragma unroll
    for (int r = 0; r < 4; r++) {
        int wrow = ctl * 16 + g * 4 + r;
        float tt = ((float)acc[r] * xs) * wsc[wrow];
        float res = ((tt + xo * wsm[wrow]) + wof[wrow] * xsmv)
                  - (xo * wof[wrow]) * 576.0f;
        out[(b * 128 + wrow) * 3136 + hw] = res;
    }
}

extern "C" void kernel_launch(void* const* d_in, const int* in_sizes, int n_in,
                              void* d_out, int out_size, void* d_ws, size_t ws_size,
                              hipStream_t stream) {
    const float* x = (const float*)d_in[0];   // [2][64][56][56]
    const float* w = (const float*)d_in[1];   // [128][64][3][3]
    float* out = (float*)d_out;               // [2][128][56][56]

    // opt-in for >64KB dynamic LDS (host-side, graph-capture-safe)
    (void)hipFuncSetAttribute((const void*)k_all,
                              hipFuncAttributeMaxDynamicSharedMemorySize, 151680);

    hipLaunchKernelGGL(k_all, dim3(196), dim3(1024), 151680, stream, x, w, out);
}

// Round 8
// 39.997 us; speedup vs baseline: 1.1984x; 1.0298x over previous
//
#include <hip/hip_runtime.h>

// ConvDatapath: bit-serial crossbar conv with per-chunk ADC quantization.
// k_wq  : one-time weight quantization -> linear fragment-layout Wq in d_ws.
// k_main: 784 blocks x 256 thr; block = (rtile, half of ctiles); per wave one
//         16x16 output tile. x quantized into stride-688 LDS scratch and read
//         as MFMA fragments directly (b128-aligned, ~2-way banks). W read
//         coalesced from global (L2). ADC + recombine bit-identical to ref.
// Nx = 6272, Ny = 128, K = 576 (5 chunks of 116, padded to 128).

#define KDIM  576
#define NPB   116
#define SSTR  688    // scratch row stride: 43*16 -> b128-aligned, 172 dw % 32 = 12

typedef int i32x4 __attribute__((ext_vector_type(4)));
typedef float f32x4 __attribute__((ext_vector_type(4)));

__device__ __forceinline__ i32x4 slice2b(i32x4 v, int sh) {
    i32x4 r;
    r[0] = (int)(((unsigned)v[0] >> sh) & 0x03030303u);
    r[1] = (int)(((unsigned)v[1] >> sh) & 0x03030303u);
    r[2] = (int)(((unsigned)v[2] >> sh) & 0x03030303u);
    r[3] = (int)(((unsigned)v[3] >> sh) & 0x03030303u);
    return r;
}

// quantize one row spread over a 16-lane group (lane i16 holds k=36*i16..+35).
// Stats via 4-step shuffle (exact); 9 dword-aligned b32 writes to scratch,
// col = k + 12*chunk (i.e. chunk*128 + k%116).
__device__ __forceinline__ void quant36(const float (&v)[36], unsigned char* rowp,
                                        int i16, float* sc, float* of,
                                        float* sm_, int sidx)
{
    float mn = v[0], mx = v[0], sm = 0.f;
#pragma unroll
    for (int m = 0; m < 36; m++) { mn = fminf(mn, v[m]); mx = fmaxf(mx, v[m]); sm += v[m]; }
#pragma unroll
    for (int off = 1; off < 16; off <<= 1) {
        mn = fminf(mn, __shfl_xor(mn, off));
        mx = fmaxf(mx, __shfl_xor(mx, off));
        sm += __shfl_xor(sm, off);
    }
    float step = (mx - mn) / 255.0f;
    if (i16 == 0) { sc[sidx] = step; of[sidx] = mn; sm_[sidx] = sm; }
    int k0 = i16 * 36;
#pragma unroll
    for (int d = 0; d < 9; d++) {
        unsigned int dw = 0;
#pragma unroll
        for (int mb = 0; mb < 4; mb++) {
            int q = (int)rintf((v[d * 4 + mb] - mn) / step);
            q = q < 0 ? 0 : (q > 255 ? 255 : q);
            dw |= (unsigned)q << (8 * mb);
        }
        int kd = k0 + d * 4;
        int ch = kd / NPB;
        *(unsigned int*)(rowp + kd + 12 * ch) = dw;
    }
}

// zero the K-pad dwords of a 16-row scratch (exactly 256 threads)
__device__ __forceinline__ void zero_pads(unsigned char* scr, int tid) {
    int rl = tid >> 4, dwp = tid & 15;
    int col = dwp < 12 ? (dwp / 3) * 128 + 116 + (dwp % 3) * 4
                       : 624 + (dwp - 12) * 4;
    *(unsigned int*)(scr + rl * SSTR + col) = 0u;
}

// ---------------- kernel 1: one-time weight quantization ----------------
__global__ __launch_bounds__(256) void k_wq(
    const float* __restrict__ w, unsigned char* __restrict__ Wq,
    float* __restrict__ wsc, float* __restrict__ wof, float* __restrict__ wsm)
{
    __shared__ __align__(16) unsigned char scrW[16 * SSTR];
    int tid = threadIdx.x, wv = tid >> 6, lane = tid & 63;
    int g = lane >> 4, i16 = lane & 15;
    int ctile = blockIdx.x;               // 0..7

    zero_pads(scrW, tid);
    __syncthreads();

    int rl = wv * 4 + g;                  // 0..15
    int row = ctile * 16 + rl;
    const float* wr = w + (size_t)row * KDIM + i16 * 36;
    float v[36];
#pragma unroll
    for (int d = 0; d < 9; d++) {
        f32x4 t = *(const f32x4*)(wr + d * 4);
        v[d*4+0] = t[0]; v[d*4+1] = t[1]; v[d*4+2] = t[2]; v[d*4+3] = t[3];
    }
    quant36(v, scrW + rl * SSTR, i16, wsc, wof, wsm, row);
    __syncthreads();

    // repack to linear fragment layout in global: byte = idx*16,
    // idx = chunk*128 + ks*64 + lgrp*16 + rl  ->  src row (idx&15), col (idx>>4)*16
    for (int idx = tid; idx < 640; idx += 256)
        *(i32x4*)(Wq + (size_t)ctile * 10240 + idx * 16) =
            *(const i32x4*)(scrW + (idx & 15) * SSTR + (idx >> 4) * 16);
}

// ---------------- kernel 2: x quant + crossbar MFMA + ADC + dequant ----------
__global__ __launch_bounds__(256) void k_main(
    const float* __restrict__ x, const unsigned char* __restrict__ Wq,
    const float* __restrict__ wscg, const float* __restrict__ wofg,
    const float* __restrict__ wsmg, float* __restrict__ out)
{
    __shared__ float xs2[64 * 57];                      // [cin][kh*18+c]
    __shared__ __align__(16) unsigned char scrX[16 * SSTR];
    __shared__ float xsc[16], xof[16], xsm[16];

    int tid = threadIdx.x, wv = tid >> 6, lane = tid & 63;
    int g = lane >> 4, i16 = lane & 15;
    int blk = blockIdx.x;                 // 0..783
    int rtile = blk >> 1, chalf = blk & 1;
    int b = rtile >= 196 ? 1 : 0;
    int pos0 = (rtile - 196 * b) * 16;
    const float* xb = x + (size_t)(b * 64) * 3136;

    // phase A: stage x stripe (flat-position layout, coalesced runs)
    for (int i = tid; i < 64 * 54; i += 256) {
        int cin = i / 54, rem = i - cin * 54;
        int kh = rem / 18;
        int gg = pos0 + (rem - kh * 18) - 1;
        float vv = 0.f;
        if (gg >= 0 && gg < 3136) {
            int hg = gg / 56, wg = gg - hg * 56;
            int r = hg - 1 + kh;
            if (r >= 0 && r < 56) vv = xb[cin * 3136 + r * 56 + wg];
        }
        xs2[cin * 57 + rem] = vv;
    }
    zero_pads(scrX, tid);
    __syncthreads();

    // phase B: x quantization, 4 rows per wave (16 lanes per row)
    {
        int i = wv * 4 + g;               // tile-local row 0..15
        int pos = pos0 + i;
        int w_ = pos - (pos / 56) * 56;
        float v[36];
#pragma unroll
        for (int m = 0; m < 36; m++) {
            int r9 = m % 9, kh = r9 / 3, kw = r9 - kh * 3;
            int cin = i16 * 4 + m / 9;
            int ww = w_ - 1 + kw;
            v[m] = (ww >= 0 && ww < 56) ? xs2[cin * 57 + kh * 18 + i + kw] : 0.f;
        }
        quant36(v, scrX + i * SSTR, i16, xsc, xof, xsm, i);
    }
    __syncthreads();

    // phase D: one 16x16 tile per wave. Swapped operands (A=W, B=X) so C/D
    // col (lane&15) = x position -> coalesced stores. X fragments read
    // directly from scrX: row = lane&15, col = chunk*128 + ks*64 + (lane>>4)*16.
    int ctl = chalf * 4 + wv;             // 0..7
    const unsigned char* Wg = Wq + (size_t)ctl * 10240;
    const unsigned char* xp = scrX + i16 * SSTR + g * 16;

    i32x4 acc = {0, 0, 0, 0};
    const i32x4 zero = {0, 0, 0, 0};

    for (int chunk = 0; chunk < 5; chunk++) {
        i32x4 ar0 = *(const i32x4*)(xp + chunk * 128);        // ks=0
        i32x4 ar1 = *(const i32x4*)(xp + chunk * 128 + 64);   // ks=1
        const i32x4* Wp = (const i32x4*)(Wg + chunk * 2048) + lane;
        i32x4 br0 = Wp[0], br1 = Wp[64];

        i32x4 wsl[4][2];
#pragma unroll
        for (int ws = 0; ws < 4; ws++) {
            wsl[ws][0] = slice2b(br0, 6 - 2 * ws);
            wsl[ws][1] = slice2b(br1, 6 - 2 * ws);
        }
#pragma unroll
        for (int is = 0; is < 4; is++) {
            int ish = 6 - 2 * is;
            i32x4 b0 = slice2b(ar0, ish);
            i32x4 b1 = slice2b(ar1, ish);
#pragma unroll
            for (int ws = 0; ws < 4; ws++) {
                i32x4 d = __builtin_amdgcn_mfma_i32_16x16x64_i8(wsl[ws][0], b0, zero, 0, 0, 0);
                d = __builtin_amdgcn_mfma_i32_16x16x64_i8(wsl[ws][1], b1, d, 0, 0, 0);
                int sh = ish + (6 - 2 * ws);
#pragma unroll
                for (int r = 0; r < 4; r++) {
                    int z = d[r];
                    z = z > 1024 ? 1024 : z;                 // ADC clip (z >= 0)
                    int r4 = (z + 1 + ((z >> 2) & 1)) & ~3;  // round-half-even, mult of 4
                    acc[r] += r4 << sh;                      // 2^(ish+wsh)
                }
            }
        }
    }

    // epilogue: D[row = w-row (g*4+r), col = x-row (i16)]; 64B coalesced runs
    float xs = xsc[i16], xo = xof[i16], xsmv = xsm[i16];
    int hw = pos0 + i16;
#pragma unroll
    for (int r = 0; r < 4; r++) {
        int wrow = ctl * 16 + g * 4 + r;
        float tt = ((float)acc[r] * xs) * wscg[wrow];
        float res = ((tt + xo * wsmg[wrow]) + wofg[wrow] * xsmv)
                  - (xo * wofg[wrow]) * 576.0f;
        out[(size_t)(b * 128 + wrow) * 3136 + hw] = res;
    }
}

extern "C" void kernel_launch(void* const* d_in, const int* in_sizes, int n_in,
                              void* d_out, int out_size, void* d_ws, size_t ws_size,
                              hipStream_t stream) {
    const float* x = (const float*)d_in[0];   // [2][64][56][56]
    const float* w = (const float*)d_in[1];   // [128][64][3][3]
    float* out = (float*)d_out;               // [2][128][56][56]

    unsigned char* Wq = (unsigned char*)d_ws; // 8*10,240 = 81,920 B
    float* wsc = (float*)(Wq + 81920);
    float* wof = wsc + 128;
    float* wsm = wof + 128;

    hipLaunchKernelGGL(k_wq, dim3(8), dim3(256), 0, stream, w, Wq, wsc, wof, wsm);
    hipLaunchKernelGGL(k_main, dim3(784), dim3(256), 0, stream,
                       x, Wq, wsc, wof, wsm, out);
}

// Round 9
// 39.602 us; speedup vs baseline: 1.2103x; 1.0100x over previous
//
#include <hip/hip_runtime.h>

// ConvDatapath: bit-serial crossbar conv with per-chunk ADC quantization.
// k_wq  : one-time weight quantization -> linear fragment-layout Wq in d_ws.
// k_main: 784 blocks x 512 thr (8 waves). Block = (rtile, cpair: 4 ctiles).
//         Wave (ctl = cpair*4 + wv&3, khalf = wv>>2): khalf0 -> chunks 0..2,
//         khalf1 -> chunks 3..4 + integer partial-combine (LDS) + epilogue.
//         K-chunk split is exact: reference sums post-ADC z over chunks.
// Nx = 6272, Ny = 128, K = 576 (5 chunks of 116, padded to 128).

#define KDIM  576
#define NPB   116
#define SSTR  688    // scratch row stride: 43*16 -> b128-aligned, 172 dw % 32 = 12

typedef int i32x4 __attribute__((ext_vector_type(4)));
typedef float f32x4 __attribute__((ext_vector_type(4)));

__device__ __forceinline__ i32x4 slice2b(i32x4 v, int sh) {
    i32x4 r;
    r[0] = (int)(((unsigned)v[0] >> sh) & 0x03030303u);
    r[1] = (int)(((unsigned)v[1] >> sh) & 0x03030303u);
    r[2] = (int)(((unsigned)v[2] >> sh) & 0x03030303u);
    r[3] = (int)(((unsigned)v[3] >> sh) & 0x03030303u);
    return r;
}

// quantize one row spread over a 16-lane group (lane i16 holds k=36*i16..+35).
// Stats via 4-step shuffle (exact); 9 dword-aligned b32 writes to scratch,
// col = k + 12*chunk (i.e. chunk*128 + k%116).
__device__ __forceinline__ void quant36(const float (&v)[36], unsigned char* rowp,
                                        int i16, float* sc, float* of,
                                        float* sm_, int sidx)
{
    float mn = v[0], mx = v[0], sm = 0.f;
#pragma unroll
    for (int m = 0; m < 36; m++) { mn = fminf(mn, v[m]); mx = fmaxf(mx, v[m]); sm += v[m]; }
#pragma unroll
    for (int off = 1; off < 16; off <<= 1) {
        mn = fminf(mn, __shfl_xor(mn, off));
        mx = fmaxf(mx, __shfl_xor(mx, off));
        sm += __shfl_xor(sm, off);
    }
    float step = (mx - mn) / 255.0f;
    if (i16 == 0) { sc[sidx] = step; of[sidx] = mn; sm_[sidx] = sm; }
    int k0 = i16 * 36;
#pragma unroll
    for (int d = 0; d < 9; d++) {
        unsigned int dw = 0;
#pragma unroll
        for (int mb = 0; mb < 4; mb++) {
            int q = (int)rintf((v[d * 4 + mb] - mn) / step);
            q = q < 0 ? 0 : (q > 255 ? 255 : q);
            dw |= (unsigned)q << (8 * mb);
        }
        int kd = k0 + d * 4;
        int ch = kd / NPB;
        *(unsigned int*)(rowp + kd + 12 * ch) = dw;
    }
}

// zero the K-pad dwords of a 16-row scratch (exactly 256 threads)
__device__ __forceinline__ void zero_pads(unsigned char* scr, int tid) {
    int rl = tid >> 4, dwp = tid & 15;
    int col = dwp < 12 ? (dwp / 3) * 128 + 116 + (dwp % 3) * 4
                       : 624 + (dwp - 12) * 4;
    *(unsigned int*)(scr + rl * SSTR + col) = 0u;
}

// ---------------- kernel 1: one-time weight quantization ----------------
__global__ __launch_bounds__(256) void k_wq(
    const float* __restrict__ w, unsigned char* __restrict__ Wq,
    float* __restrict__ wsc, float* __restrict__ wof, float* __restrict__ wsm)
{
    __shared__ __align__(16) unsigned char scrW[16 * SSTR];
    int tid = threadIdx.x, wv = tid >> 6, lane = tid & 63;
    int g = lane >> 4, i16 = lane & 15;
    int ctile = blockIdx.x;               // 0..7

    zero_pads(scrW, tid);
    __syncthreads();

    int rl = wv * 4 + g;                  // 0..15
    int row = ctile * 16 + rl;
    const float* wr = w + (size_t)row * KDIM + i16 * 36;
    float v[36];
#pragma unroll
    for (int d = 0; d < 9; d++) {
        f32x4 t = *(const f32x4*)(wr + d * 4);
        v[d*4+0] = t[0]; v[d*4+1] = t[1]; v[d*4+2] = t[2]; v[d*4+3] = t[3];
    }
    quant36(v, scrW + rl * SSTR, i16, wsc, wof, wsm, row);
    __syncthreads();

    // repack to linear fragment layout in global: byte = idx*16,
    // idx = chunk*128 + ks*64 + lgrp*16 + rl -> src row (idx&15), col (idx>>4)*16
    for (int idx = tid; idx < 640; idx += 256)
        *(i32x4*)(Wq + (size_t)ctile * 10240 + idx * 16) =
            *(const i32x4*)(scrW + (idx & 15) * SSTR + (idx >> 4) * 16);
}

// ---------------- kernel 2: x quant + crossbar MFMA + ADC + dequant ----------
__global__ __launch_bounds__(512) void k_main(
    const float* __restrict__ x, const unsigned char* __restrict__ Wq,
    const float* __restrict__ wscg, const float* __restrict__ wofg,
    const float* __restrict__ wsmg, float* __restrict__ out)
{
    __shared__ float xs2[64 * 57];                      // [cin][kh*18+c]
    __shared__ __align__(16) unsigned char scrX[16 * SSTR];
    __shared__ float xsc[16], xof[16], xsm[16];
    __shared__ __align__(16) int pacc[4][64][4];        // khalf0 partials

    int tid = threadIdx.x, wv = tid >> 6, lane = tid & 63;
    int g = lane >> 4, i16 = lane & 15;
    int blk = blockIdx.x;                 // 0..783
    int rtile = blk >> 1, cpair = blk & 1;
    int b = rtile >= 196 ? 1 : 0;
    int pos0 = (rtile - 196 * b) * 16;
    const float* xb = x + (size_t)(b * 64) * 3136;

    // phase A: stage x stripe (flat-position layout, coalesced runs)
    for (int i = tid; i < 64 * 54; i += 512) {
        int cin = i / 54, rem = i - cin * 54;
        int kh = rem / 18;
        int gg = pos0 + (rem - kh * 18) - 1;
        float vv = 0.f;
        if (gg >= 0 && gg < 3136) {
            int hg = gg / 56, wg = gg - hg * 56;
            int r = hg - 1 + kh;
            if (r >= 0 && r < 56) vv = xb[cin * 3136 + r * 56 + wg];
        }
        xs2[cin * 57 + rem] = vv;
    }
    if (tid < 256) zero_pads(scrX, tid);
    __syncthreads();

    // phase B: x quantization by waves 0..3, 4 rows each (16 lanes per row)
    if (wv < 4) {
        int i = wv * 4 + g;               // tile-local row 0..15
        int pos = pos0 + i;
        int w_ = pos - (pos / 56) * 56;
        float v[36];
#pragma unroll
        for (int m = 0; m < 36; m++) {
            int r9 = m % 9, kh = r9 / 3, kw = r9 - kh * 3;
            int cin = i16 * 4 + m / 9;
            int ww = w_ - 1 + kw;
            v[m] = (ww >= 0 && ww < 56) ? xs2[cin * 57 + kh * 18 + i + kw] : 0.f;
        }
        quant36(v, scrX + i * SSTR, i16, xsc, xof, xsm, i);
    }
    __syncthreads();

    // phase D: wave = (ctl, khalf). khalf0 -> chunks 0..2; khalf1 -> 3..4.
    // Swapped operands (A=W, B=X): C/D col (lane&15) = x position.
    // X fragment: row = lane&15, col = chunk*128 + ks*64 + (lane>>4)*16.
    int ctl = cpair * 4 + (wv & 3);
    int khalf = wv >> 2;
    const unsigned char* Wg = Wq + (size_t)ctl * 10240;
    const unsigned char* xp = scrX + i16 * SSTR + g * 16;

    i32x4 acc = {0, 0, 0, 0};
    const i32x4 zero = {0, 0, 0, 0};
    int cbeg = khalf ? 3 : 0, cend = khalf ? 5 : 3;

    for (int chunk = cbeg; chunk < cend; chunk++) {
        i32x4 ar0 = *(const i32x4*)(xp + chunk * 128);        // ks=0
        i32x4 ar1 = *(const i32x4*)(xp + chunk * 128 + 64);   // ks=1
        const i32x4* Wp = (const i32x4*)(Wg + chunk * 2048) + lane;
        i32x4 br0 = Wp[0], br1 = Wp[64];

        i32x4 wsl[4][2];
#pragma unroll
        for (int ws = 0; ws < 4; ws++) {
            wsl[ws][0] = slice2b(br0, 6 - 2 * ws);
            wsl[ws][1] = slice2b(br1, 6 - 2 * ws);
        }
#pragma unroll
        for (int is = 0; is < 4; is++) {
            int ish = 6 - 2 * is;
            i32x4 b0 = slice2b(ar0, ish);
            i32x4 b1 = slice2b(ar1, ish);
#pragma unroll
            for (int ws = 0; ws < 4; ws++) {
                i32x4 d = __builtin_amdgcn_mfma_i32_16x16x64_i8(wsl[ws][0], b0, zero, 0, 0, 0);
                d = __builtin_amdgcn_mfma_i32_16x16x64_i8(wsl[ws][1], b1, d, 0, 0, 0);
                int sh = ish + (6 - 2 * ws);
#pragma unroll
                for (int r = 0; r < 4; r++) {
                    int z = d[r];
                    z = z > 1024 ? 1024 : z;                 // ADC clip (z >= 0)
                    int t = (z >> 2) & 1;                    // v_bfe
                    int r4 = (z + 1 + t) & ~3;               // round-half-even, mult of 4
                    acc[r] += r4 << sh;                      // v_lshl_add
                }
            }
        }
    }

    if (khalf == 0)
        *(i32x4*)&pacc[wv & 3][lane][0] = acc;   // lane-linear b128, conflict-free
    __syncthreads();

    if (khalf == 1) {
        i32x4 p = *(const i32x4*)&pacc[wv & 3][lane][0];
#pragma unroll
        for (int r = 0; r < 4; r++) acc[r] += p[r];   // integer chunk-sum: exact

        // epilogue: D[row = w-row (g*4+r), col = x-row (i16)]; 64B coalesced
        float xs = xsc[i16], xo = xof[i16], xsmv = xsm[i16];
        int hw = pos0 + i16;
#pragma unroll
        for (int r = 0; r < 4; r++) {
            int wrow = ctl * 16 + g * 4 + r;
            float tt = ((float)acc[r] * xs) * wscg[wrow];
            float res = ((tt + xo * wsmg[wrow]) + wofg[wrow] * xsmv)
                      - (xo * wofg[wrow]) * 576.0f;
            out[(size_t)(b * 128 + wrow) * 3136 + hw] = res;
        }
    }
}

extern "C" void kernel_launch(void* const* d_in, const int* in_sizes, int n_in,
                              void* d_out, int out_size, void* d_ws, size_t ws_size,
                              hipStream_t stream) {
    const float* x = (const float*)d_in[0];   // [2][64][56][56]
    const float* w = (const float*)d_in[1];   // [128][64][3][3]
    float* out = (float*)d_out;               // [2][128][56][56]

    unsigned char* Wq = (unsigned char*)d_ws; // 8*10,240 = 81,920 B
    float* wsc = (float*)(Wq + 81920);
    float* wof = wsc + 128;
    float* wsm = wof + 128;

    hipLaunchKernelGGL(k_wq, dim3(8), dim3(256), 0, stream, w, Wq, wsc, wof, wsm);
    hipLaunchKernelGGL(k_main, dim3(784), dim3(512), 0, stream,
                       x, Wq, wsc, wof, wsm, out);
}